// Round 4
// baseline (159.492 us; speedup 1.0000x reference)
//
#include <hip/hip_runtime.h>

#define B_DIM 1024
#define C_DIM 256
#define ELL   9
#define E_DIM 10
#define K1    1
#define K2    4
#define K3    20

#define N_CUBIC 165            // C(9+2,3) monomials a<=b<=c
#define N_QUAD  45             // pairs a<=b
#define ROW3    80             // [l0 k0..19][v0 k0..19][v1][v2]
#define ROW2    16             // [l0 k0..3][v0][v1][v2]
#define ROW1    4              // [l0][v0][v1][v2]
#define T3_OFF  0
#define T2_OFF  (N_CUBIC * ROW3)            // 13200
#define T1_OFF  (T2_OFF + N_QUAD * ROW2)    // 13920
#define TBL_TOTAL (T1_OFF + ELL * ROW1)     // 13956 floats

// ---------------------------------------------------------------------------
// Kernel A: build symmetrized product-basis tables into d_ws. (validated r1)
// ---------------------------------------------------------------------------
__global__ void build_tables(const float* __restrict__ U1_l0,
                             const float* __restrict__ U2_l0,
                             const float* __restrict__ U3_l0,
                             const float* __restrict__ U1_l1,
                             const float* __restrict__ U2_l1,
                             const float* __restrict__ U3_l1,
                             float* __restrict__ tbl)
{
    int idx = blockIdx.x * blockDim.x + threadIdx.x;
    if (idx >= TBL_TOTAL) return;

    if (idx < T2_OFF) {
        int m = idx / ROW3, j = idx % ROW3;
        int a = 0, b = 0, c = 0, cnt = 0;
        for (int ai = 0; ai < ELL; ++ai)
            for (int bi = ai; bi < ELL; ++bi)
                for (int ci = bi; ci < ELL; ++ci) {
                    if (cnt == m) { a = ai; b = bi; c = ci; }
                    ++cnt;
                }
        int P[6][3] = {{a,b,c},{a,c,b},{b,a,c},{b,c,a},{c,a,b},{c,b,a}};
        float s = 0.f;
        for (int t = 0; t < 6; ++t) {
            bool dup = false;
            for (int u = 0; u < t; ++u)
                if (P[u][0]==P[t][0] && P[u][1]==P[t][1] && P[u][2]==P[t][2]) { dup = true; break; }
            if (dup) continue;
            int p0 = P[t][0], p1 = P[t][1], p2 = P[t][2];
            if (j < K3) {
                s += U3_l0[((p0*ELL + p1)*ELL + p2)*K3 + j];
            } else {
                int j2 = j - K3; int w = j2 / K3; int k = j2 % K3;
                s += U3_l1[(((w*ELL + p0)*ELL + p1)*ELL + p2)*K3 + k];
            }
        }
        tbl[idx] = s;
    } else if (idx < T1_OFF) {
        int r = idx - T2_OFF;
        int p = r / ROW2, j = r % ROW2;
        int a = 0, b = 0, cnt = 0;
        for (int ai = 0; ai < ELL; ++ai)
            for (int bi = ai; bi < ELL; ++bi) {
                if (cnt == p) { a = ai; b = bi; }
                ++cnt;
            }
        float s = 0.f;
        for (int t = 0; t < 2; ++t) {
            if (t == 1 && a == b) break;
            int p0 = (t == 0) ? a : b;
            int p1 = (t == 0) ? b : a;
            if (j < K2) {
                s += U2_l0[(p0*ELL + p1)*K2 + j];
            } else {
                int j2 = j - K2; int w = j2 / K2; int k = j2 % K2;
                s += U2_l1[((w*ELL + p0)*ELL + p1)*K2 + k];
            }
        }
        tbl[idx] = s;
    } else {
        int r = idx - T1_OFF;
        int i = r / ROW1, j = r % ROW1;
        float s;
        if (j == 0) s = U1_l0[i];
        else        s = U1_l1[(j - 1)*ELL + i];
        tbl[idx] = s;
    }
}

// ---------------------------------------------------------------------------
// Kernel B v4: 1024-thread block per b; q = readfirstlane(tid>>8) selects the
// output channel group (scalar table pointer -> s_load path). Monomial loops
// are ROLLED (small I$ footprint, ~25-inst body); x is staged in LDS so the
// runtime (a,b2,c2) indices never touch a register array (rule #20).
// LDS = 60.4 KB -> exactly 2 blocks/CU -> 32 waves/CU = 8 waves/SIMD, enough
// TLP to cover the ~250cy s_load latency per 20-float table row (40cy FMA).
// ---------------------------------------------------------------------------
#define WT_K (K3 + K2 + K1)     // 25 channels per parity

__global__ __launch_bounds__(1024) void symcon_main(
    const float* __restrict__ x,  const float* __restrict__ y,
    const float* __restrict__ w1_l0, const float* __restrict__ w2_l0, const float* __restrict__ w3_l0,
    const float* __restrict__ w1_l1, const float* __restrict__ w2_l1, const float* __restrict__ w3_l1,
    const float* __restrict__ tbl, float* __restrict__ out)
{
    const int b   = blockIdx.x;
    const int tid = threadIdx.x;
    const int q   = __builtin_amdgcn_readfirstlane(tid >> 8);  // SGPR: 0..3
    const int c   = tid & 255;

    // rows 0..24 = l1 (k3:0..19, k2:20..23, k1:24); rows 25..49 = l0 same order
    __shared__ float wt[2 * WT_K][C_DIM];   // 51.2 KB
    __shared__ float xs[ELL][C_DIM];        //  9.2 KB

    // ---- stage x ----
    for (int t = tid; t < ELL * C_DIM; t += 1024) {
        int i  = t >> 8;
        int cc = t & 255;
        xs[i][cc] = x[(size_t)(b*C_DIM + cc)*ELL + i];
    }

    // ---- cooperative staging of weighted weights ----
    {
        float yb[E_DIM];
        #pragma unroll
        for (int e = 0; e < E_DIM; ++e) yb[e] = y[b*E_DIM + e];

        for (int t = tid; t < 2 * WT_K * C_DIM; t += 1024) {
            int k  = t >> 8;        // 0..49
            int cc = t & 255;
            int par = (k >= WT_K);  // 0 = l1, 1 = l0
            int kk  = par ? (k - WT_K) : k;
            float s = 0.f;
            if (kk < K3) {
                const float* wp = par ? w3_l0 : w3_l1;
                #pragma unroll
                for (int e = 0; e < E_DIM; ++e)
                    s = fmaf(yb[e], wp[(e*K3 + kk)*C_DIM + cc], s);
            } else if (kk < K3 + K2) {
                const float* wp = par ? w2_l0 : w2_l1;
                int k2 = kk - K3;
                #pragma unroll
                for (int e = 0; e < E_DIM; ++e)
                    s = fmaf(yb[e], wp[(e*K2 + k2)*C_DIM + cc], s);
            } else {
                const float* wp = par ? w1_l0 : w1_l1;
                #pragma unroll
                for (int e = 0; e < E_DIM; ++e)
                    s = fmaf(yb[e], wp[e*C_DIM + cc], s);
            }
            wt[k][cc] = s;
        }
    }
    __syncthreads();

    float acc3[K3];
    #pragma unroll
    for (int j = 0; j < K3; ++j) acc3[j] = 0.f;
    float acc2[K2];
    #pragma unroll
    for (int j = 0; j < K2; ++j) acc2[j] = 0.f;
    float acc1 = 0.f;

    // ---- cubic: 165 monomials, rolled; uniform row pointer -> s_load ----
    {
        const float* row = tbl + T3_OFF + q*K3;
        for (int a = 0; a < ELL; ++a) {
            float xa = xs[a][c];
            for (int b2 = a; b2 < ELL; ++b2) {
                float xab = xa * xs[b2][c];
                for (int c2 = b2; c2 < ELL; ++c2) {
                    float x3 = xab * xs[c2][c];
                    #pragma unroll
                    for (int j = 0; j < K3; ++j)
                        acc3[j] = fmaf(row[j], x3, acc3[j]);
                    row += ROW3;
                }
            }
        }
    }
    // ---- quadratic: 45 monomials, rolled ----
    {
        const float* row = tbl + T2_OFF + q*K2;
        for (int a = 0; a < ELL; ++a) {
            float xa = xs[a][c];
            for (int b2 = a; b2 < ELL; ++b2) {
                float x2 = xa * xs[b2][c];
                #pragma unroll
                for (int j = 0; j < K2; ++j)
                    acc2[j] = fmaf(row[j], x2, acc2[j]);
                row += ROW2;
            }
        }
    }
    // ---- linear ----
    {
        const float* row = tbl + T1_OFF + q*K1;
        #pragma unroll
        for (int i = 0; i < ELL; ++i)
            acc1 = fmaf(row[i*ROW1], xs[i][c], acc1);
    }

    // ---- combine: pure LDS reads for every q-group ----
    const float* wrow = (q == 0) ? &wt[WT_K][0] : &wt[0][0];  // scalar select
    float o = 0.f;
    #pragma unroll
    for (int k = 0; k < K3; ++k)
        o = fmaf(wrow[k*C_DIM + c], acc3[k], o);
    #pragma unroll
    for (int k = 0; k < K2; ++k)
        o = fmaf(wrow[(K3 + k)*C_DIM + c], acc2[k], o);
    o = fmaf(wrow[(K3 + K2)*C_DIM + c], acc1, o);

    if (q == 0) {
        out[b*C_DIM + c] = o;
    } else {
        out[B_DIM*C_DIM + (size_t)(b*C_DIM + c)*3 + (q - 1)] = o;
    }
}

// ---------------------------------------------------------------------------
extern "C" void kernel_launch(void* const* d_in, const int* in_sizes, int n_in,
                              void* d_out, int out_size, void* d_ws, size_t ws_size,
                              hipStream_t stream)
{
    const float* x     = (const float*)d_in[0];
    const float* y     = (const float*)d_in[1];
    const float* U1_l0 = (const float*)d_in[2];
    const float* U2_l0 = (const float*)d_in[3];
    const float* U3_l0 = (const float*)d_in[4];
    const float* U1_l1 = (const float*)d_in[5];
    const float* U2_l1 = (const float*)d_in[6];
    const float* U3_l1 = (const float*)d_in[7];
    const float* w1_l0 = (const float*)d_in[8];
    const float* w2_l0 = (const float*)d_in[9];
    const float* w3_l0 = (const float*)d_in[10];
    const float* w1_l1 = (const float*)d_in[11];
    const float* w2_l1 = (const float*)d_in[12];
    const float* w3_l1 = (const float*)d_in[13];

    float* tbl  = (float*)d_ws;
    float* outp = (float*)d_out;

    build_tables<<<(TBL_TOTAL + 255)/256, 256, 0, stream>>>(
        U1_l0, U2_l0, U3_l0, U1_l1, U2_l1, U3_l1, tbl);

    symcon_main<<<B_DIM, 1024, 0, stream>>>(
        x, y, w1_l0, w2_l0, w3_l0, w1_l1, w2_l1, w3_l1, tbl, outp);
}